// Round 1
// baseline (781.976 us; speedup 1.0000x reference)
//
#include <hip/hip_runtime.h>
#include <math.h>

#define Bsz 1024
#define PADL 127
#define HID 512
#define NBb 128
#define NYd 8
#define INDIM 640
#define MTRIP 10
#define MROW 8
#define NBNY 1024
#define FOURH 2048

__device__ __forceinline__ float sigf(float x){ return 1.0f/(1.0f+expf(-x)); }

// ---- yard feasibility: any(encoder_mask, axis=-1) & ~block_mask, early exit ----
__global__ __launch_bounds__(256) void yard_kernel(const int* __restrict__ em,
                                                   const int* __restrict__ bmask,
                                                   int* __restrict__ valid)
{
    int r = blockIdx.x*256 + threadIdx.x;
    if (r >= Bsz*NBb*NYd) return;
    const int* p = em + (size_t)r*PADL;
    int any = 0;
    #pragma unroll 1
    for (int j=0; j<PADL; ++j){ if (p[j]!=0){ any=1; break; } }
    int bn = r / NYd;                 // b*NB + nb
    valid[r] = (any && (bmask[bn]==0)) ? 1 : 0;
}

// ---- gates = x@Wih^T + h0@Whh^T + bih + bhh  (1024 x 2048, K=640 then 512) ----
__global__ __launch_bounds__(256) void gemm_gates(const float* __restrict__ x,
    const float* __restrict__ h0, const float* __restrict__ Wih,
    const float* __restrict__ Whh, const float* __restrict__ bih,
    const float* __restrict__ bhh, float* __restrict__ gates)
{
    __shared__ float As[16][68];
    __shared__ float Bs[16][68];
    const int tid = threadIdx.x;
    const int m0 = blockIdx.y*64, n0 = blockIdx.x*64;
    const int lm = tid>>2, lk = (tid&3)*4;
    const int tm = (tid>>4)*4, tn = (tid&15)*4;
    float acc[4][4] = {{0.f,0.f,0.f,0.f},{0.f,0.f,0.f,0.f},{0.f,0.f,0.f,0.f},{0.f,0.f,0.f,0.f}};

    // phase 1: x (lda=640) with Wih
    {
        const float* Arow = x   + (m0+lm)*INDIM + lk;
        const float* Brow = Wih + (n0+lm)*INDIM + lk;
        for (int k0=0; k0<INDIM; k0+=16){
            float4 av = *(const float4*)(Arow + k0);
            float4 bv = *(const float4*)(Brow + k0);
            As[lk+0][lm]=av.x; As[lk+1][lm]=av.y; As[lk+2][lm]=av.z; As[lk+3][lm]=av.w;
            Bs[lk+0][lm]=bv.x; Bs[lk+1][lm]=bv.y; Bs[lk+2][lm]=bv.z; Bs[lk+3][lm]=bv.w;
            __syncthreads();
            #pragma unroll
            for (int kk=0; kk<16; ++kk){
                float4 a = *(const float4*)&As[kk][tm];
                float4 b = *(const float4*)&Bs[kk][tn];
                float a4[4]={a.x,a.y,a.z,a.w}, b4[4]={b.x,b.y,b.z,b.w};
                #pragma unroll
                for (int i=0;i<4;i++)
                    #pragma unroll
                    for (int j=0;j<4;j++) acc[i][j] += a4[i]*b4[j];
            }
            __syncthreads();
        }
    }
    // phase 2: h0 (lda=512) with Whh
    {
        const float* Arow = h0  + (m0+lm)*HID + lk;
        const float* Brow = Whh + (n0+lm)*HID + lk;
        for (int k0=0; k0<HID; k0+=16){
            float4 av = *(const float4*)(Arow + k0);
            float4 bv = *(const float4*)(Brow + k0);
            As[lk+0][lm]=av.x; As[lk+1][lm]=av.y; As[lk+2][lm]=av.z; As[lk+3][lm]=av.w;
            Bs[lk+0][lm]=bv.x; Bs[lk+1][lm]=bv.y; Bs[lk+2][lm]=bv.z; Bs[lk+3][lm]=bv.w;
            __syncthreads();
            #pragma unroll
            for (int kk=0; kk<16; ++kk){
                float4 a = *(const float4*)&As[kk][tm];
                float4 b = *(const float4*)&Bs[kk][tn];
                float a4[4]={a.x,a.y,a.z,a.w}, b4[4]={b.x,b.y,b.z,b.w};
                #pragma unroll
                for (int i=0;i<4;i++)
                    #pragma unroll
                    for (int j=0;j<4;j++) acc[i][j] += a4[i]*b4[j];
            }
            __syncthreads();
        }
    }
    #pragma unroll
    for (int i=0;i<4;i++){
        int row = m0+tm+i;
        #pragma unroll
        for (int j=0;j<4;j++){
            int col = n0+tn+j;
            gates[row*FOURH + col] = acc[i][j] + bih[col] + bhh[col];
        }
    }
}

// ---- logits = h@Wfc^T + bfc  (1024 x 1024, K=512) ----
__global__ __launch_bounds__(256) void gemm_fc(const float* __restrict__ h,
    const float* __restrict__ Wfc, const float* __restrict__ bfc,
    float* __restrict__ logits)
{
    __shared__ float As[16][68];
    __shared__ float Bs[16][68];
    const int tid = threadIdx.x;
    const int m0 = blockIdx.y*64, n0 = blockIdx.x*64;
    const int lm = tid>>2, lk = (tid&3)*4;
    const int tm = (tid>>4)*4, tn = (tid&15)*4;
    float acc[4][4] = {{0.f,0.f,0.f,0.f},{0.f,0.f,0.f,0.f},{0.f,0.f,0.f,0.f},{0.f,0.f,0.f,0.f}};

    const float* Arow = h   + (m0+lm)*HID + lk;
    const float* Brow = Wfc + (n0+lm)*HID + lk;
    for (int k0=0; k0<HID; k0+=16){
        float4 av = *(const float4*)(Arow + k0);
        float4 bv = *(const float4*)(Brow + k0);
        As[lk+0][lm]=av.x; As[lk+1][lm]=av.y; As[lk+2][lm]=av.z; As[lk+3][lm]=av.w;
        Bs[lk+0][lm]=bv.x; Bs[lk+1][lm]=bv.y; Bs[lk+2][lm]=bv.z; Bs[lk+3][lm]=bv.w;
        __syncthreads();
        #pragma unroll
        for (int kk=0; kk<16; ++kk){
            float4 a = *(const float4*)&As[kk][tm];
            float4 b = *(const float4*)&Bs[kk][tn];
            float a4[4]={a.x,a.y,a.z,a.w}, b4[4]={b.x,b.y,b.z,b.w};
            #pragma unroll
            for (int i=0;i<4;i++)
                #pragma unroll
                for (int j=0;j<4;j++) acc[i][j] += a4[i]*b4[j];
        }
        __syncthreads();
    }
    #pragma unroll
    for (int i=0;i<4;i++){
        int row = m0+tm+i;
        #pragma unroll
        for (int j=0;j<4;j++){
            int col = n0+tn+j;
            logits[row*NBNY + col] = acc[i][j] + bfc[col];
        }
    }
}

// ---- LSTM elementwise: h = sig(o)*tanh(sig(f)*c0 + sig(i)*tanh(g)) ----
__global__ __launch_bounds__(256) void lstm_kernel(const float* __restrict__ gates,
    const float* __restrict__ c0, float* __restrict__ h)
{
    int idx = blockIdx.x*256 + threadIdx.x;       // < 1024*512
    int b = idx >> 9, j = idx & 511;
    const float* g = gates + b*FOURH;
    float ig = g[j], fg = g[512+j], gg = g[1024+j], og = g[1536+j];
    float c = sigf(fg)*c0[idx] + sigf(ig)*tanhf(gg);
    h[idx] = sigf(og)*tanhf(c);
}

// ---- masked softmax over 1024 cols + first-max argmax ----
__global__ __launch_bounds__(256) void softmax_kernel(const float* __restrict__ logits,
    const int* __restrict__ valid, float* __restrict__ probs, int* __restrict__ action)
{
    int b = blockIdx.x, t = threadIdx.x;
    __shared__ float red[256];
    __shared__ int  redi[256];
    const float* lrow = logits + b*NBNY;
    const int*   vrow = valid  + b*NBNY;
    float ml[4]; float mymax = -INFINITY;
    #pragma unroll
    for (int r=0;r<4;++r){
        int c = t + r*256;
        float m = (vrow[c]!=0) ? lrow[c] : -1e9f;
        ml[r] = m; mymax = fmaxf(mymax, m);
    }
    red[t]=mymax; __syncthreads();
    for (int s=128;s>0;s>>=1){ if(t<s) red[t]=fmaxf(red[t],red[t+s]); __syncthreads(); }
    float rowmax = red[0]; __syncthreads();
    float p[4]; float mysum=0.f;
    #pragma unroll
    for (int r=0;r<4;++r){ p[r]=expf(ml[r]-rowmax); mysum+=p[r]; }
    red[t]=mysum; __syncthreads();
    for (int s=128;s>0;s>>=1){ if(t<s) red[t]+=red[t+s]; __syncthreads(); }
    float inv = 1.0f/red[0]; __syncthreads();
    float bv=-INFINITY; int bi=0;
    #pragma unroll
    for (int r=0;r<4;++r){
        int c = t + r*256;
        float pr = p[r]*inv;
        probs[b*NBNY + c] = pr;
        if (pr > bv){ bv=pr; bi=c; }     // in-thread cols ascend -> strict > = first max
    }
    red[t]=bv; redi[t]=bi; __syncthreads();
    for (int s=128;s>0;s>>=1){
        if (t<s){
            float ov=red[t+s]; int oi=redi[t+s];
            if (ov>red[t] || (ov==red[t] && oi<redi[t])){ red[t]=ov; redi[t]=oi; }
        }
        __syncthreads();
    }
    if (t==0) action[b]=redi[0];
}

// ---- per-sample action decode ----
__global__ __launch_bounds__(256) void decode_kernel(const int* __restrict__ action,
    const int* __restrict__ bcount, const float* __restrict__ bsize,
    const float* __restrict__ bwid_in, const float* __restrict__ blen_in,
    int* __restrict__ pslot, int* __restrict__ pblock,
    float* __restrict__ pblen, float* __restrict__ pbwid)
{
    int b = blockIdx.x*256 + threadIdx.x;
    if (b >= Bsz) return;
    int a = action[b];
    int blk = a / NYd, yard = a % NYd;
    int cur = bcount[b*NYd + yard];
    int base = ((b*NYd + yard)*MTRIP + cur)*MROW;
    float bestv = -INFINITY; int bests = 0;
    #pragma unroll
    for (int s=0;s<MROW;++s){
        float w = bwid_in[base+s];
        float l = blen_in[base+s];
        float cand = (w <= 10.0f) ? l : -1.0f;
        if (cand > bestv){ bestv=cand; bests=s; }   // first max
    }
    pslot[b]  = base + bests;
    pblock[b] = blk;
    pblen[b]  = bsize[(b*NBb + blk)*5 + 0];
    pbwid[b]  = bsize[(b*NBb + blk)*5 + 1];
}

// ---- copy inputs -> outputs with single-element patches ----
__global__ __launch_bounds__(256) void finalize_kernel(const int* __restrict__ bslot,
    const float* __restrict__ blen_in, const float* __restrict__ bwid_in,
    const int* __restrict__ pslot, const int* __restrict__ pblock,
    const float* __restrict__ pblen, const float* __restrict__ pbwid,
    float* __restrict__ out_slot, float* __restrict__ out_len, float* __restrict__ out_wid)
{
    int i = blockIdx.x*256 + threadIdx.x;
    if (i < Bsz*NYd*MTRIP*MROW*2){               // 1,310,720
        int b = i / (NYd*MTRIP*MROW*2);          // /1280
        float v = (float)bslot[i];
        if (i == pslot[b]*2 + 1) v = (float)pblock[b];
        out_slot[i] = v;
    }
    if (i < Bsz*NYd*MTRIP*MROW){                 // 655,360
        int b = i / (NYd*MTRIP*MROW);            // /640
        float l = blen_in[i], w = bwid_in[i];
        if (i == pslot[b]){ l = fmaxf(l, pblen[b]); w = w + pbwid[b]; }
        out_len[i] = l;
        out_wid[i] = w;
    }
}

extern "C" void kernel_launch(void* const* d_in, const int* in_sizes, int n_in,
                              void* d_out, int out_size, void* d_ws, size_t ws_size,
                              hipStream_t stream)
{
    const float* x    = (const float*)d_in[0];
    const float* h0   = (const float*)d_in[1];
    const float* c0   = (const float*)d_in[2];
    const float* Wih  = (const float*)d_in[3];
    const float* Whh  = (const float*)d_in[4];
    const float* bih  = (const float*)d_in[5];
    const float* bhh  = (const float*)d_in[6];
    const float* Wfc  = (const float*)d_in[7];
    const float* bfc  = (const float*)d_in[8];
    const float* bsize= (const float*)d_in[9];
    const float* blen = (const float*)d_in[10];
    const float* bwid = (const float*)d_in[11];
    const int*   em   = (const int*)d_in[12];
    const int*   bmask= (const int*)d_in[13];
    const int*   bcount=(const int*)d_in[14];
    const int*   bslot= (const int*)d_in[15];

    float* out      = (float*)d_out;
    float* probs    = out;                                  // 1,048,576
    float* out_slot = out + 1048576;                        // 1,310,720
    float* out_len  = out + 1048576 + 1310720;              // 655,360
    float* out_wid  = out_len + 655360;                     // 655,360

    float* ws     = (float*)d_ws;
    float* gates  = ws;                      // 2,097,152 f32
    float* h      = ws + 2097152;            //   524,288
    float* logits = ws + 2621440;            // 1,048,576
    int*   valid  = (int*)(ws + 3670016);    // 1,048,576
    int*   action = (int*)(ws + 4718592);    // 1024
    int*   pslot  = (int*)(ws + 4719616);    // 1024
    int*   pblock = (int*)(ws + 4720640);    // 1024
    float* pblen  = ws + 4721664;            // 1024
    float* pbwid  = ws + 4722688;            // 1024

    yard_kernel<<<4096, 256, 0, stream>>>(em, bmask, valid);
    gemm_gates<<<dim3(32,16), 256, 0, stream>>>(x, h0, Wih, Whh, bih, bhh, gates);
    lstm_kernel<<<2048, 256, 0, stream>>>(gates, c0, h);
    gemm_fc<<<dim3(16,16), 256, 0, stream>>>(h, Wfc, bfc, logits);
    softmax_kernel<<<1024, 256, 0, stream>>>(logits, valid, probs, action);
    decode_kernel<<<4, 256, 0, stream>>>(action, bcount, bsize, bwid, blen,
                                         pslot, pblock, pblen, pbwid);
    finalize_kernel<<<5120, 256, 0, stream>>>(bslot, blen, bwid, pslot, pblock, pblen, pbwid,
                                              out_slot, out_len, out_wid);
}